// Round 5
// baseline (708.827 us; speedup 1.0000x reference)
//
#include <hip/hip_runtime.h>
#include <hip/hip_bf16.h>

#define BB 2
#define CC 512
#define HH 14
#define WW 14
#define PP 196
#define NSEQ 8
#define NSLICE 16        // channel slices per row (32 ch each)
#define NWORK (14 * NSLICE)
#define FSTR 16          // flag stride (uints): one cache line per cell

// ---------------------------------------------------------------------------
// prep: gemm_a (224 WGs) + transpose_wh (256 WGs) + flag zero (1 WG)
// ---------------------------------------------------------------------------
__global__ __launch_bounds__(256) void prep(
    const float* __restrict__ Wx, const float* __restrict__ X,
    const float* __restrict__ b_in, const float* __restrict__ Wh,
    float* __restrict__ A, float* __restrict__ WhT,
    unsigned* __restrict__ uflag, unsigned* __restrict__ hflag) {
    __shared__ float Ws[32][33], Xs[32][33];
    int bid = blockIdx.x;
    int t = threadIdx.x;
    if (bid < 224) {
        int z = bid / 112, rem = bid % 112;
        int c0 = (rem % 16) * 32, p0 = (rem / 16) * 32;
        int tx = t % 32, ty = t / 32;
        int pl = (t % 16) * 2, cl = (t / 16) * 2;
        float acc[2][2] = {{0.f,0.f},{0.f,0.f}};
        for (int k0 = 0; k0 < CC; k0 += 32) {
            #pragma unroll
            for (int r = 0; r < 4; ++r)
                Ws[ty + 8*r][tx] = Wx[(size_t)(c0 + ty + 8*r) * CC + k0 + tx];
            #pragma unroll
            for (int r = 0; r < 4; ++r) {
                int p = p0 + tx, k = k0 + ty + 8*r;
                Xs[ty + 8*r][tx] = (p < PP) ? X[((size_t)z * CC + k) * PP + p] : 0.f;
            }
            __syncthreads();
            #pragma unroll
            for (int k = 0; k < 32; ++k) {
                float w0 = Ws[cl][k], w1 = Ws[cl+1][k];
                float x0 = Xs[k][pl], x1 = Xs[k][pl+1];
                acc[0][0] += w0*x0; acc[0][1] += w0*x1;
                acc[1][0] += w1*x0; acc[1][1] += w1*x1;
            }
            __syncthreads();
        }
        #pragma unroll
        for (int i = 0; i < 2; ++i)
            #pragma unroll
            for (int j = 0; j < 2; ++j) {
                int c = c0 + cl + i, p = p0 + pl + j;
                if (p < PP) A[((size_t)z * PP + p) * CC + c] = acc[i][j] + b_in[c];
            }
    } else if (bid < 480) {
        int tid = bid - 224;
        int c0 = (tid % 16) * 32, k0 = (tid / 16) * 32;
        int tx = t % 32, ty = t / 32;
        #pragma unroll
        for (int r = 0; r < 4; ++r)
            Ws[ty + 8*r][tx] = Wh[(size_t)(c0 + ty + 8*r) * CC + k0 + tx];
        __syncthreads();
        #pragma unroll
        for (int r = 0; r < 4; ++r)
            WhT[(size_t)(k0 + ty + 8*r) * CC + c0 + tx] = Ws[tx][ty + 8*r];
    } else {
        if (t < PP) { uflag[t * FSTR] = 0u; hflag[t * FSTR] = 0u; }
    }
}

// ---------------------------------------------------------------------------
// wave-level flag wait (device-scope RMW poll; lane 0 only, lanes converge)
// ---------------------------------------------------------------------------
__device__ __forceinline__ void wait_flag(unsigned* f, int lane, unsigned want) {
    if (lane == 0) {
        unsigned r = atomicAdd(f, 0u);
        while (r < want) { __builtin_amdgcn_s_sleep(2); r = atomicAdd(f, 0u); }
    }
    asm volatile("" ::: "memory");
}

// one window pixel for 8 channels x this wave's seq
__device__ __forceinline__ void pix(const float4 U0, const float4 U1,
                                    const float* ar, const float* er, float* hacc) {
    float uu[8] = {U0.x,U0.y,U0.z,U0.w,U1.x,U1.y,U1.z,U1.w};
    float ds = 0.f, tl[8];
    #pragma unroll
    for (int j = 0; j < 8; ++j) {
        float sv = ar[j] + uu[j];            // a + U
        float pv = er[j] * __expf(uu[j]);    // exp(a+U)
        ds += fmaxf(pv, 1.0f);               // exp(relu(a+U))
        tl[j] = fmaxf(sv, 0.0f) * pv;        // z * exp(z)
    }
    #pragma unroll
    for (int off = 32; off; off >>= 1) ds += __shfl_xor(ds, off, 64);
    float rd = 1.0f / ds;
    #pragma unroll
    for (int j = 0; j < 8; ++j) hacc[j] += tl[j] * rd;
}

// process n pixels at rowp + y*CC (y=0..n-1), 4-deep double-buffered loads
__device__ __forceinline__ void proc_row(const float* __restrict__ rowp, int n,
                                         const float* ar, const float* er, float* hacc) {
    float4 cur[4][2];
    int y = 0, curn = (n < 4) ? n : 4;
    #pragma unroll
    for (int i = 0; i < 4; ++i) if (i < curn) {
        cur[i][0] = *(const float4*)(rowp + (size_t)i * CC);
        cur[i][1] = *(const float4*)(rowp + (size_t)i * CC + 256);
    }
    while (true) {
        int yn = y + curn;
        int rem = n - yn;
        int nextn = (rem < 4) ? rem : 4;
        float4 nxt[4][2];
        #pragma unroll
        for (int i = 0; i < 4; ++i) if (i < nextn) {
            nxt[i][0] = *(const float4*)(rowp + (size_t)(yn + i) * CC);
            nxt[i][1] = *(const float4*)(rowp + (size_t)(yn + i) * CC + 256);
        }
        #pragma unroll
        for (int i = 0; i < 4; ++i) if (i < curn)
            pix(cur[i][0], cur[i][1], ar, er, hacc);
        if (nextn <= 0) break;
        #pragma unroll
        for (int i = 0; i < 4; ++i) if (i < nextn) {
            cur[i][0] = nxt[i][0]; cur[i][1] = nxt[i][1];
        }
        curn = nextn; y = yn;
    }
}

// ---------------------------------------------------------------------------
// One kernel, two roles:
//   blockIdx 0..223   : persistent matvec workers (row px = bid>>4, 32-ch slice)
//   blockIdx 224..419 : per-cell window WGs (wave = seq)
// All 420 WGs co-resident by capacity: <=128 VGPR, 27.8KB LDS -> 2 WG/CU.
// ---------------------------------------------------------------------------
__global__ __launch_bounds__(512, 4) void rnn_dataflow(
    const float* __restrict__ A, const float* __restrict__ WhT,
    float* __restrict__ U, float* __restrict__ h_t,
    float* __restrict__ Hst, unsigned* __restrict__ uflag,
    unsigned* __restrict__ hflag) {
    __shared__ float hT[CC][13];     // h transposed [k][s]; stride 13 = conflict-free
    __shared__ float ured[32][9];
    int bid = blockIdx.x;
    int t = threadIdx.x;

    if (bid < NWORK) {
        // ================= persistent worker =================
        int px = bid >> 4, w = bid & 15;
        int ksub = t & 31, quad = t >> 5;        // quad 0..15
        int c0 = w * 32 + quad * 2;
        float wreg[2][16];
        #pragma unroll
        for (int ci = 0; ci < 2; ++ci)
            #pragma unroll
            for (int j = 0; j < 16; ++j)
                wreg[ci][j] = WhT[(size_t)(ksub + 32*j) * CC + c0 + ci];
        __builtin_amdgcn_s_setprio(1);           // critical-path waves win issue

        for (int py = 0; py < WW; ++py) {
            int cell = px * WW + py;
            if (cell == PP - 1) break;           // U(13,13) has no consumer
            if (t == 0) {
                unsigned r = atomicAdd(hflag + cell * FSTR, 0u);
                while (r == 0u) {
                    __builtin_amdgcn_s_sleep(2);
                    r = atomicAdd(hflag + cell * FSTR, 0u);
                }
            }
            __syncthreads();

            // stage h_t[cell][k][8] -> hT[k][0..7] (coalesced)
            const float* hp = h_t + (size_t)cell * (CC * 8);
            float4 v0 = *(const float4*)(hp + t*8);
            float4 v1 = *(const float4*)(hp + t*8 + 4);
            *(float4*)&hT[t][0] = v0;
            *(float4*)&hT[t][4] = v1;
            __syncthreads();

            float acc[2][8];
            #pragma unroll
            for (int ci = 0; ci < 2; ++ci)
                #pragma unroll
                for (int ss = 0; ss < 8; ++ss) acc[ci][ss] = 0.f;
            #pragma unroll
            for (int j = 0; j < 16; ++j) {
                int k = ksub + 32*j;
                float4 h0 = *(const float4*)&hT[k][0];
                float4 h1 = *(const float4*)&hT[k][4];
                float hh[8] = {h0.x,h0.y,h0.z,h0.w,h1.x,h1.y,h1.z,h1.w};
                #pragma unroll
                for (int ci = 0; ci < 2; ++ci) {
                    float wv = wreg[ci][j];
                    #pragma unroll
                    for (int ss = 0; ss < 8; ++ss) acc[ci][ss] += wv * hh[ss];
                }
            }
            #pragma unroll
            for (int off = 1; off < 32; off <<= 1)
                #pragma unroll
                for (int ci = 0; ci < 2; ++ci)
                    #pragma unroll
                    for (int ss = 0; ss < 8; ++ss)
                        acc[ci][ss] += __shfl_xor(acc[ci][ss], off, 64);
            if (ksub == 0)
                #pragma unroll
                for (int ci = 0; ci < 2; ++ci)
                    #pragma unroll
                    for (int ss = 0; ss < 8; ++ss)
                        ured[quad*2 + ci][ss] = acc[ci][ss];
            __syncthreads();
            if (t < 256) {      // coalesced agent-scope publish (write-through)
                int s = t >> 5, cl = t & 31;
                __hip_atomic_store(&U[((size_t)s * PP + cell) * CC + w*32 + cl],
                                   ured[cl][s], __ATOMIC_RELAXED,
                                   __HIP_MEMORY_SCOPE_AGENT);
            }
            __syncthreads();    // per-wave vmcnt drained before barrier
            if (t == 0) atomicAdd(uflag + cell * FSTR, 1u);
        }
    } else {
        // ================= per-cell window WG =================
        int cell = bid - NWORK;
        int px = cell / WW, py = cell % WW;
        int wave = t >> 6, lane = t & 63;
        int s = wave, m = s >> 1, b = s & 1;
        int fi = (m & 2) ? (HH-1-px) : px;
        int fj = (m & 1) ? (WW-1-py) : py;
        int cb = lane * 4;

        const float* acur = A + ((size_t)b * PP + fi * WW + fj) * CC;
        float4 a0 = *(const float4*)(acur + cb);
        float4 a1 = *(const float4*)(acur + cb + 256);
        float ar[8] = {a0.x,a0.y,a0.z,a0.w,a1.x,a1.y,a1.z,a1.w};
        float er[8];
        #pragma unroll
        for (int j = 0; j < 8; ++j) er[j] = __expf(ar[j]);
        float hacc[8] = {0.f,0.f,0.f,0.f,0.f,0.f,0.f,0.f};

        const float* Ub = U + (size_t)s * PP * CC;
        // rows 0..px-1 cover y<=py; row px covers y<py. Worker row x publishes
        // cells in ascending y, so uflag(x, ylast) transitively covers the row.
        for (int x = 0; x <= px; ++x) {
            int ylim = (x < px) ? (py + 1) : py;
            if (ylim == 0) break;                  // only x==px, py==0
            wait_flag(uflag + (x * WW + (ylim - 1)) * FSTR, lane, NSLICE);
            proc_row(Ub + (size_t)(x * WW) * CC + cb, ylim, ar, er, hacc);
        }
        {   // self pixel: U=0, exp(U)=1
            float ds = 0.f, tl[8];
            #pragma unroll
            for (int j = 0; j < 8; ++j) {
                float pv = er[j];
                ds += fmaxf(pv, 1.0f);
                tl[j] = fmaxf(ar[j], 0.0f) * pv;
            }
            #pragma unroll
            for (int off = 32; off; off >>= 1) ds += __shfl_xor(ds, off, 64);
            float rd = 1.0f / ds;
            #pragma unroll
            for (int j = 0; j < 8; ++j) hacc[j] += tl[j] * rd;
        }

        // publish h (k-major x 8 seqs, agent scope) + Hst (plain, next kernel)
        float* hp = h_t + (size_t)cell * (CC * 8);
        #pragma unroll
        for (int j = 0; j < 4; ++j) {
            __hip_atomic_store(&hp[(cb + j) * 8 + s], hacc[j],
                               __ATOMIC_RELAXED, __HIP_MEMORY_SCOPE_AGENT);
            __hip_atomic_store(&hp[(cb + 256 + j) * 8 + s], hacc[4 + j],
                               __ATOMIC_RELAXED, __HIP_MEMORY_SCOPE_AGENT);
        }
        size_t ob = ((size_t)s * PP + cell) * CC;
        *(float4*)&Hst[ob + cb]       = make_float4(hacc[0],hacc[1],hacc[2],hacc[3]);
        *(float4*)&Hst[ob + cb + 256] = make_float4(hacc[4],hacc[5],hacc[6],hacc[7]);
        __syncthreads();        // drain all waves' stores before publish
        if (t == 0) atomicAdd(hflag + cell * FSTR, 1u);
    }
}

// ---------------------------------------------------------------------------
// gemm_y: Y[b][p][c] = sum_k Wo[c][k] * (sum_m Hst[m*2+b][p][k]) + 4*b_out[c]
// ---------------------------------------------------------------------------
__global__ __launch_bounds__(256) void gemm_y(
    const float* __restrict__ Wo, const float* __restrict__ Hst,
    const float* __restrict__ b_out, float* __restrict__ Y) {
    __shared__ float Ws[32][33], Hs[32][33];
    int b  = blockIdx.z;
    int c0 = blockIdx.x * 32, p0 = blockIdx.y * 32;
    int t  = threadIdx.x;
    int tx = t % 32, ty = t / 32;
    int pl = (t % 16) * 2, cl = (t / 16) * 2;
    float acc[2][2] = {{0.f,0.f},{0.f,0.f}};
    for (int k0 = 0; k0 < CC; k0 += 32) {
        #pragma unroll
        for (int r = 0; r < 4; ++r)
            Ws[ty + 8*r][tx] = Wo[(size_t)(c0 + ty + 8*r) * CC + k0 + tx];
        #pragma unroll
        for (int r = 0; r < 4; ++r) {
            int p = p0 + ty + 8*r;
            float v = 0.f;
            if (p < PP) {
                size_t base = (size_t)p * CC + k0 + tx;
                v = Hst[((size_t)(0*2 + b) * PP) * CC + base]
                  + Hst[((size_t)(1*2 + b) * PP) * CC + base]
                  + Hst[((size_t)(2*2 + b) * PP) * CC + base]
                  + Hst[((size_t)(3*2 + b) * PP) * CC + base];
            }
            Hs[tx][ty + 8*r] = v;
        }
        __syncthreads();
        #pragma unroll
        for (int k = 0; k < 32; ++k) {
            float w0 = Ws[cl][k], w1 = Ws[cl+1][k];
            float h0 = Hs[k][pl], h1 = Hs[k][pl+1];
            acc[0][0] += w0*h0; acc[0][1] += w0*h1;
            acc[1][0] += w1*h0; acc[1][1] += w1*h1;
        }
        __syncthreads();
    }
    #pragma unroll
    for (int i = 0; i < 2; ++i)
        #pragma unroll
        for (int j = 0; j < 2; ++j) {
            int cc = c0 + cl + i, p = p0 + pl + j;
            if (p < PP) Y[((size_t)b * PP + p) * CC + cc] = acc[i][j] + 4.0f * b_out[cc];
        }
}

// ---------------------------------------------------------------------------
// softmax over channels -> out[b][c][p]
// ---------------------------------------------------------------------------
__global__ __launch_bounds__(256) void softmax_out(
    const float* __restrict__ Y, float* __restrict__ out) {
    int wave = threadIdx.x >> 6, lane = threadIdx.x & 63;
    int idx = blockIdx.x * 4 + wave;
    if (idx >= BB * PP) return;
    int b = idx / PP, p = idx % PP;
    const float* y = Y + ((size_t)b * PP + p) * CC;
    float v[8];
    float mx = -3.4e38f;
    #pragma unroll
    for (int j = 0; j < 8; ++j) { v[j] = y[lane + 64*j]; mx = fmaxf(mx, v[j]); }
    #pragma unroll
    for (int off = 32; off; off >>= 1) mx = fmaxf(mx, __shfl_xor(mx, off, 64));
    float sum = 0.f;
    #pragma unroll
    for (int j = 0; j < 8; ++j) { v[j] = expf(v[j] - mx); sum += v[j]; }
    #pragma unroll
    for (int off = 32; off; off >>= 1) sum += __shfl_xor(sum, off, 64);
    float r = 1.0f / sum;
    #pragma unroll
    for (int j = 0; j < 8; ++j)
        out[((size_t)b * CC + lane + 64*j) * PP + p] = v[j] * r;
}

// ---------------------------------------------------------------------------
extern "C" void kernel_launch(void* const* d_in, const int* in_sizes, int n_in,
                              void* d_out, int out_size, void* d_ws, size_t ws_size,
                              hipStream_t stream) {
    const float* X     = (const float*)d_in[0];
    const float* Wx    = (const float*)d_in[1];
    const float* Wh    = (const float*)d_in[2];
    const float* b_in  = (const float*)d_in[3];
    const float* Wo    = (const float*)d_in[4];
    const float* b_out = (const float*)d_in[5];
    float* out = (float*)d_out;

    float* ws  = (float*)d_ws;
    float* WhT = ws;                        // 262144
    float* A   = WhT + 262144;              // 200704
    float* U   = A   + 200704;              // 802816  [s][cell][c]
    float* h_t = U   + 802816;              // 802816  [cell][k][8]
    float* Hst = h_t + 802816;              // 802816  [s][cell][c]
    float* Y   = Hst + 802816;              // 200704
    unsigned* uflag = (unsigned*)(Y + 200704);      // 196*FSTR
    unsigned* hflag = uflag + PP * FSTR;            // 196*FSTR

    hipLaunchKernelGGL(prep, dim3(481), dim3(256), 0, stream,
                       Wx, X, b_in, Wh, A, WhT, uflag, hflag);
    hipLaunchKernelGGL(rnn_dataflow, dim3(NWORK + PP), dim3(512), 0, stream,
                       A, WhT, U, h_t, Hst, uflag, hflag);
    hipLaunchKernelGGL(gemm_y, dim3(16, 7, 2), dim3(256), 0, stream, Wo, Hst, b_out, Y);
    hipLaunchKernelGGL(softmax_out, dim3(98), dim3(256), 0, stream, Y, out);
}

// Round 7
// 541.216 us; speedup vs baseline: 1.3097x; 1.3097x over previous
//
#include <hip/hip_runtime.h>
#include <hip/hip_bf16.h>

#define BB 2
#define CC 512
#define HH 14
#define WW 14
#define PP 196
#define NSEQ 8
#define NSLICE 16                // worker WGs per row (32 ch each)
#define NWORK (14 * NSLICE)      // 224
#define FSTR 16                  // flag stride (uints): one line per cell

// ---------------------------------------------------------------------------
// prep: gemm_a (224 WGs) + transpose_wh (256 WGs) + flag zero (1 WG)
// ---------------------------------------------------------------------------
__global__ __launch_bounds__(256) void prep(
    const float* __restrict__ Wx, const float* __restrict__ X,
    const float* __restrict__ b_in, const float* __restrict__ Wh,
    float* __restrict__ A, float* __restrict__ WhT,
    unsigned* __restrict__ uflag, unsigned* __restrict__ hflag) {
    __shared__ float Ws[32][33], Xs[32][33];
    int bid = blockIdx.x;
    int t = threadIdx.x;
    if (bid < 224) {
        int z = bid / 112, rem = bid % 112;
        int c0 = (rem % 16) * 32, p0 = (rem / 16) * 32;
        int tx = t % 32, ty = t / 32;
        int pl = (t % 16) * 2, cl = (t / 16) * 2;
        float acc[2][2] = {{0.f,0.f},{0.f,0.f}};
        for (int k0 = 0; k0 < CC; k0 += 32) {
            #pragma unroll
            for (int r = 0; r < 4; ++r)
                Ws[ty + 8*r][tx] = Wx[(size_t)(c0 + ty + 8*r) * CC + k0 + tx];
            #pragma unroll
            for (int r = 0; r < 4; ++r) {
                int p = p0 + tx, k = k0 + ty + 8*r;
                Xs[ty + 8*r][tx] = (p < PP) ? X[((size_t)z * CC + k) * PP + p] : 0.f;
            }
            __syncthreads();
            #pragma unroll
            for (int k = 0; k < 32; ++k) {
                float w0 = Ws[cl][k], w1 = Ws[cl+1][k];
                float x0 = Xs[k][pl], x1 = Xs[k][pl+1];
                acc[0][0] += w0*x0; acc[0][1] += w0*x1;
                acc[1][0] += w1*x0; acc[1][1] += w1*x1;
            }
            __syncthreads();
        }
        #pragma unroll
        for (int i = 0; i < 2; ++i)
            #pragma unroll
            for (int j = 0; j < 2; ++j) {
                int c = c0 + cl + i, p = p0 + pl + j;
                if (p < PP) A[((size_t)z * PP + p) * CC + c] = acc[i][j] + b_in[c];
            }
    } else if (bid < 480) {
        int tid = bid - 224;
        int c0 = (tid % 16) * 32, k0 = (tid / 16) * 32;
        int tx = t % 32, ty = t / 32;
        #pragma unroll
        for (int r = 0; r < 4; ++r)
            Ws[ty + 8*r][tx] = Wh[(size_t)(c0 + ty + 8*r) * CC + k0 + tx];
        __syncthreads();
        #pragma unroll
        for (int r = 0; r < 4; ++r)
            WhT[(size_t)(k0 + ty + 8*r) * CC + c0 + tx] = Ws[tx][ty + 8*r];
    } else {
        if (t < PP) { uflag[t * FSTR] = 0u; hflag[t * FSTR] = 0u; }
    }
}

// ---------------------------------------------------------------------------
// sync primitives
// ---------------------------------------------------------------------------
__device__ __forceinline__ unsigned flag_ld(const unsigned* f) {
    return __hip_atomic_load(f, __ATOMIC_RELAXED, __HIP_MEMORY_SCOPE_AGENT);
}
// wave-level wait: lane 0 spins on an agent-scope LOAD (no RMW contention)
__device__ __forceinline__ void wait_cnt(const unsigned* f, int lane, unsigned want) {
    if (lane == 0) {
        while (flag_ld(f) < want) __builtin_amdgcn_s_sleep(1);
    }
    asm volatile("" ::: "memory");
}
// agent-scope write-through store, dword granularity (coalesced across lanes)
__device__ __forceinline__ void store_wt(float* p, float v) {
    __hip_atomic_store(p, v, __ATOMIC_RELAXED, __HIP_MEMORY_SCOPE_AGENT);
}

// one window pixel for 8 channels (this wave's seq); E = exp(U) input
__device__ __forceinline__ void pix(const float4 E0, const float4 E1,
                                    const float* ar, const float* er, float* hacc) {
    float ee[8] = {E0.x,E0.y,E0.z,E0.w,E1.x,E1.y,E1.z,E1.w};
    float ds = 0.f, tl[8];
    #pragma unroll
    for (int j = 0; j < 8; ++j) {
        float sv = ar[j] + __logf(ee[j]);    // a + U   (log(0)=-inf -> tl=0 ok)
        float pv = er[j] * ee[j];            // exp(a+U)
        ds += fmaxf(pv, 1.0f);               // exp(relu(a+U))
        tl[j] = fmaxf(sv, 0.0f) * pv;        // z * exp(z)
    }
    #pragma unroll
    for (int off = 32; off; off >>= 1) ds += __shfl_xor(ds, off, 64);
    float rd = 1.0f / ds;
    #pragma unroll
    for (int j = 0; j < 8; ++j) hacc[j] += tl[j] * rd;
}

// process n pixels at rowp + y*CC, 4-deep pipelined plain loads
__device__ __forceinline__ void proc_row(const float* __restrict__ rowp, int n,
                                         const float* ar, const float* er, float* hacc) {
    float4 cur[4][2];
    int y = 0, curn = (n < 4) ? n : 4;
    #pragma unroll
    for (int i = 0; i < 4; ++i) if (i < curn) {
        cur[i][0] = *(const float4*)(rowp + (size_t)i * CC);
        cur[i][1] = *(const float4*)(rowp + (size_t)i * CC + 256);
    }
    while (true) {
        int yn = y + curn;
        int rem = n - yn;
        int nextn = (rem < 4) ? rem : 4;
        float4 nxt[4][2];
        #pragma unroll
        for (int i = 0; i < 4; ++i) if (i < nextn) {
            nxt[i][0] = *(const float4*)(rowp + (size_t)(yn + i) * CC);
            nxt[i][1] = *(const float4*)(rowp + (size_t)(yn + i) * CC + 256);
        }
        #pragma unroll
        for (int i = 0; i < 4; ++i) if (i < curn)
            pix(cur[i][0], cur[i][1], ar, er, hacc);
        if (nextn <= 0) break;
        #pragma unroll
        for (int i = 0; i < 4; ++i) if (i < nextn) {
            cur[i][0] = nxt[i][0]; cur[i][1] = nxt[i][1];
        }
        curn = nextn; y = yn;
    }
}

// ---------------------------------------------------------------------------
// One kernel, two roles:
//   blockIdx 0..223   : persistent matvec workers (row = bid>>4, 32-ch slice)
//   blockIdx 224..419 : per-cell window WGs (wave = seq, fully independent)
// 420 WGs, <=128 VGPR, <20KB LDS -> 2 WG/CU -> all co-resident by capacity.
// ---------------------------------------------------------------------------
__global__ __launch_bounds__(512, 4) void rnn_dataflow(
    const float* __restrict__ A, const float* __restrict__ WhT,
    float* __restrict__ E, float* __restrict__ h_t,
    unsigned* __restrict__ uflag, unsigned* __restrict__ hflag) {
    __shared__ float hT[CC * 9];     // [k][s] rows of 9 dwords: conflict-free
    __shared__ float ured[32][9];
    int bid = blockIdx.x;
    int t = threadIdx.x;

    if (bid < NWORK) {
        // ================= persistent worker =================
        int px = bid >> 4, w = bid & 15;
        int ksub = t & 31, quad = t >> 5;        // 32 k-lanes x 16 c-pairs
        int c0 = w * 32 + quad * 2;
        float wreg[2][16];
        #pragma unroll
        for (int ci = 0; ci < 2; ++ci)
            #pragma unroll
            for (int j = 0; j < 16; ++j)
                wreg[ci][j] = WhT[(size_t)(ksub + 32*j) * CC + c0 + ci];
        __builtin_amdgcn_s_setprio(1);

        for (int py = 0; py < WW; ++py) {
            int cell = px * WW + py;
            if (cell == PP - 1) break;           // (13,13) has no consumer
            if (t == 0) {
                while (flag_ld(hflag + cell * FSTR) < 8u)
                    __builtin_amdgcn_s_sleep(1);
            }
            __syncthreads();
            asm volatile("" ::: "memory");

            // stage h_t[cell][s][k] -> hT[k*9+s] (coalesced loads, CF writes)
            const float* hp = h_t + (size_t)cell * (CC * NSEQ);
            #pragma unroll
            for (int s = 0; s < 8; ++s) {
                float hv = hp[(size_t)s * CC + t];
                hT[t * 9 + s] = hv;
            }
            __syncthreads();

            float acc[2][8];
            #pragma unroll
            for (int ci = 0; ci < 2; ++ci)
                #pragma unroll
                for (int ss = 0; ss < 8; ++ss) acc[ci][ss] = 0.f;
            #pragma unroll
            for (int j = 0; j < 16; ++j) {
                int k = ksub + 32*j;
                float hh[8];
                #pragma unroll
                for (int ss = 0; ss < 8; ++ss) hh[ss] = hT[k * 9 + ss];
                #pragma unroll
                for (int ci = 0; ci < 2; ++ci) {
                    float wv = wreg[ci][j];
                    #pragma unroll
                    for (int ss = 0; ss < 8; ++ss) acc[ci][ss] += wv * hh[ss];
                }
            }
            #pragma unroll
            for (int off = 1; off < 32; off <<= 1)
                #pragma unroll
                for (int ci = 0; ci < 2; ++ci)
                    #pragma unroll
                    for (int ss = 0; ss < 8; ++ss)
                        acc[ci][ss] += __shfl_xor(acc[ci][ss], off, 64);
            if (ksub == 0)
                #pragma unroll
                for (int ci = 0; ci < 2; ++ci)
                    #pragma unroll
                    for (int ss = 0; ss < 8; ++ss)
                        ured[quad*2 + ci][ss] = acc[ci][ss];
            __syncthreads();
            if (t < 256) {      // E = exp(U), coalesced agent WT dword stores
                int s = t >> 5, cl = t & 31;
                float ev = __expf(ured[cl][s]);
                store_wt(&E[((size_t)s * PP + cell) * CC + w*32 + cl], ev);
            }
            __syncthreads();    // all waves' stores drained before publish
            if (t == 0) atomicAdd(uflag + cell * FSTR, 1u);
        }
    } else {
        // ================= per-cell window WG (per-wave independent) ========
        int cell = bid - NWORK;
        int px = cell / WW, py = cell % WW;
        int wave = t >> 6, lane = t & 63;
        int s = wave, m = s >> 1, b = s & 1;
        int fi = (m & 2) ? (HH-1-px) : px;
        int fj = (m & 1) ? (WW-1-py) : py;
        int cb = lane * 4;

        const float* acur = A + ((size_t)b * PP + fi * WW + fj) * CC;
        float4 a0 = *(const float4*)(acur + cb);
        float4 a1 = *(const float4*)(acur + cb + 256);
        float ar[8] = {a0.x,a0.y,a0.z,a0.w,a1.x,a1.y,a1.z,a1.w};
        float er[8];
        #pragma unroll
        for (int j = 0; j < 8; ++j) er[j] = __expf(ar[j]);
        float hacc[8] = {0.f,0.f,0.f,0.f,0.f,0.f,0.f,0.f};

        const float* Eb = E + (size_t)s * PP * CC;
        // Phase 1: everything with >=2 hops of slack.
        //   rows x<=px-2: y<=py ; row px-1: y<=py-1 ; row px: y<=py-2
        for (int x = 0; x <= px; ++x) {
            int yl = (x <= px-2) ? py : ((x == px-1) ? py-1 : py-2);
            if (yl < 0) continue;
            wait_cnt(uflag + (x * WW + yl) * FSTR, lane, NSLICE);
            proc_row(Eb + (size_t)(x * WW) * CC + cb, yl + 1, ar, er, hacc);
        }
        // Phase 2: the two d-1 critical pixels.
        __builtin_amdgcn_s_setprio(1);
        if (px >= 1) {
            int q = (px-1) * WW + py;
            wait_cnt(uflag + q * FSTR, lane, NSLICE);
            const float4* ep = (const float4*)(Eb + (size_t)q * CC + cb);
            pix(ep[0], ep[64], ar, er, hacc);
        }
        if (py >= 1) {
            int q = px * WW + (py-1);
            wait_cnt(uflag + q * FSTR, lane, NSLICE);
            const float4* ep = (const float4*)(Eb + (size_t)q * CC + cb);
            pix(ep[0], ep[64], ar, er, hacc);
        }
        {   // self pixel: U=0 -> E=1
            float ds = 0.f, tl[8];
            #pragma unroll
            for (int j = 0; j < 8; ++j) {
                float pv = er[j];
                ds += fmaxf(pv, 1.0f);
                tl[j] = fmaxf(ar[j], 0.0f) * pv;
            }
            #pragma unroll
            for (int off = 32; off; off >>= 1) ds += __shfl_xor(ds, off, 64);
            float rd = 1.0f / ds;
            #pragma unroll
            for (int j = 0; j < 8; ++j) hacc[j] += tl[j] * rd;
        }

        // per-wave release publish: coalesced agent WT stores + waitcnt + RMW
        float* hp = h_t + ((size_t)cell * NSEQ + s) * CC;
        #pragma unroll
        for (int j = 0; j < 4; ++j) {
            store_wt(hp + cb + j,       hacc[j]);
            store_wt(hp + cb + 256 + j, hacc[4 + j]);
        }
        __builtin_amdgcn_s_waitcnt(0);
        asm volatile("" ::: "memory");
        if (lane == 0) atomicAdd(hflag + cell * FSTR, 1u);
    }
}

// ---------------------------------------------------------------------------
// gemm_y: Y[b][p][c] = sum_k Wo[c][k] * (sum_m h_t[p][2m+b][k]) + 4*b_out[c]
// ---------------------------------------------------------------------------
__global__ __launch_bounds__(256) void gemm_y(
    const float* __restrict__ Wo, const float* __restrict__ h_t,
    const float* __restrict__ b_out, float* __restrict__ Y) {
    __shared__ float Ws[32][33], Hs[32][33];
    int b  = blockIdx.z;
    int c0 = blockIdx.x * 32, p0 = blockIdx.y * 32;
    int t  = threadIdx.x;
    int tx = t % 32, ty = t / 32;
    int pl = (t % 16) * 2, cl = (t / 16) * 2;
    float acc[2][2] = {{0.f,0.f},{0.f,0.f}};
    for (int k0 = 0; k0 < CC; k0 += 32) {
        #pragma unroll
        for (int r = 0; r < 4; ++r)
            Ws[ty + 8*r][tx] = Wo[(size_t)(c0 + ty + 8*r) * CC + k0 + tx];
        #pragma unroll
        for (int r = 0; r < 4; ++r) {
            int p = p0 + ty + 8*r;
            float v = 0.f;
            if (p < PP) {
                size_t base = (size_t)p * NSEQ * CC + k0 + tx;
                v = h_t[base + (size_t)(0 + b) * CC]
                  + h_t[base + (size_t)(2 + b) * CC]
                  + h_t[base + (size_t)(4 + b) * CC]
                  + h_t[base + (size_t)(6 + b) * CC];
            }
            Hs[tx][ty + 8*r] = v;
        }
        __syncthreads();
        #pragma unroll
        for (int k = 0; k < 32; ++k) {
            float w0 = Ws[cl][k], w1 = Ws[cl+1][k];
            float h0 = Hs[k][pl], h1 = Hs[k][pl+1];
            acc[0][0] += w0*h0; acc[0][1] += w0*h1;
            acc[1][0] += w1*h0; acc[1][1] += w1*h1;
        }
        __syncthreads();
    }
    #pragma unroll
    for (int i = 0; i < 2; ++i)
        #pragma unroll
        for (int j = 0; j < 2; ++j) {
            int cc = c0 + cl + i, p = p0 + pl + j;
            if (p < PP) Y[((size_t)b * PP + p) * CC + cc] = acc[i][j] + 4.0f * b_out[cc];
        }
}

// ---------------------------------------------------------------------------
// softmax over channels -> out[b][c][p]
// ---------------------------------------------------------------------------
__global__ __launch_bounds__(256) void softmax_out(
    const float* __restrict__ Y, float* __restrict__ out) {
    int wave = threadIdx.x >> 6, lane = threadIdx.x & 63;
    int idx = blockIdx.x * 4 + wave;
    if (idx >= BB * PP) return;
    int b = idx / PP, p = idx % PP;
    const float* y = Y + ((size_t)b * PP + p) * CC;
    float v[8];
    float mx = -3.4e38f;
    #pragma unroll
    for (int j = 0; j < 8; ++j) { v[j] = y[lane + 64*j]; mx = fmaxf(mx, v[j]); }
    #pragma unroll
    for (int off = 32; off; off >>= 1) mx = fmaxf(mx, __shfl_xor(mx, off, 64));
    float sum = 0.f;
    #pragma unroll
    for (int j = 0; j < 8; ++j) { v[j] = expf(v[j] - mx); sum += v[j]; }
    #pragma unroll
    for (int off = 32; off; off >>= 1) sum += __shfl_xor(sum, off, 64);
    float r = 1.0f / sum;
    #pragma unroll
    for (int j = 0; j < 8; ++j)
        out[((size_t)b * CC + lane + 64*j) * PP + p] = v[j] * r;
}

// ---------------------------------------------------------------------------
extern "C" void kernel_launch(void* const* d_in, const int* in_sizes, int n_in,
                              void* d_out, int out_size, void* d_ws, size_t ws_size,
                              hipStream_t stream) {
    const float* X     = (const float*)d_in[0];
    const float* Wx    = (const float*)d_in[1];
    const float* Wh    = (const float*)d_in[2];
    const float* b_in  = (const float*)d_in[3];
    const float* Wo    = (const float*)d_in[4];
    const float* b_out = (const float*)d_in[5];
    float* out = (float*)d_out;

    float* ws  = (float*)d_ws;
    float* WhT = ws;                        // 262144
    float* A   = WhT + 262144;              // 200704
    float* E   = A   + 200704;              // 802816  [s][cell][c] = exp(U)
    float* h_t = E   + 802816;              // 802816  [cell][s][k]
    float* Y   = h_t + 802816;              // 200704
    unsigned* uflag = (unsigned*)(Y + 200704);      // 196*FSTR
    unsigned* hflag = uflag + PP * FSTR;            // 196*FSTR

    hipLaunchKernelGGL(prep, dim3(481), dim3(256), 0, stream,
                       Wx, X, b_in, Wh, A, WhT, uflag, hflag);
    hipLaunchKernelGGL(rnn_dataflow, dim3(NWORK + PP), dim3(512), 0, stream,
                       A, WhT, E, h_t, uflag, hflag);
    hipLaunchKernelGGL(gemm_y, dim3(16, 7, 2), dim3(256), 0, stream, Wo, h_t, b_out, Y);
    hipLaunchKernelGGL(softmax_out, dim3(98), dim3(256), 0, stream, Y, out);
}